// Round 6
// baseline (152.597 us; speedup 1.0000x reference)
//
#include <hip/hip_runtime.h>

// BlockSparseAttention B=2,H=16,N=2048,D=64 fp32, block-causal.
// R6: single-wave WGs (no barriers), 32x32x16 MFMA (halves LDS/VALU/MFMA per row),
// fine-grained vmcnt-pipelined DMA double-buffer, 2048 WGs LPT-ordered for
// queue-based balancing. V^T image carries a bits2<->3 key permutation so
// P (S^T C-layout) feeds PV A-operand as a register rename.

typedef short bf16x8 __attribute__((ext_vector_type(8)));
typedef float f32x16 __attribute__((ext_vector_type(16)));
typedef unsigned short u16;
typedef u16 u16x8 __attribute__((ext_vector_type(8)));

#define MFMA32(A,B,C) __builtin_amdgcn_mfma_f32_32x32x16_bf16((A),(B),(C),0,0,0)

__device__ __forceinline__ u16 f2bf_rne(float f) {
    union { float f; unsigned u; } c; c.f = f;
    unsigned r = c.u + 0x7FFFu + ((c.u >> 16) & 1u);
    return (u16)(r >> 16);
}
__device__ __forceinline__ u16 f2bf_fast(float f) {
    union { float f; unsigned u; } c; c.f = f;
    return (u16)((c.u + 0x8000u) >> 16);
}
__device__ __forceinline__ void gload_lds16(const void* g, void* lds) {
    __builtin_amdgcn_global_load_lds(
        (const __attribute__((address_space(1))) unsigned int*)g,
        (__attribute__((address_space(3))) unsigned int*)lds, 16, 0, 0);
}

// ---- prepass: per (bh, 64-key tile) 16KB blob ----
// K-image: K[key][8ch..+8) stored at u16 idx key*64 + ((ch+key)&7)*8
// V-image: slot sl holds V[key = sl with bits2<->3 swapped]; value at (d, sl):
//          u16 idx 4096 + d*64 + (((sl>>3) + (d&7) + 2*((d>>4)&3))&7)*8 + (sl&7)
__global__ __launch_bounds__(256)
void prep_kernel(const float* __restrict__ K, const float* __restrict__ V,
                 u16* __restrict__ blob)
{
    int bt = blockIdx.x;                 // bh*32 + tile
    int tid = threadIdx.x;
    const size_t gbase = (size_t)bt * 4096;
    u16* bb = blob + (size_t)bt * 8192;
    __shared__ __align__(16) u16 lt[4096];

    int key = tid >> 2;
    int dg  = tid & 3;                   // d-group of 16
    // K path: coalesced loads, scattered 16B global stores (L2-merged)
    {
        int c2 = dg << 1;                // chunks c2, c2+1
        const float* kp = K + gbase + key * 64 + c2 * 8;
        float4 x0 = *(const float4*)kp,       x1 = *(const float4*)(kp + 4);
        float4 x2 = *(const float4*)(kp + 8), x3 = *(const float4*)(kp + 12);
        u16x8 a, b;
        a[0]=f2bf_rne(x0.x); a[1]=f2bf_rne(x0.y); a[2]=f2bf_rne(x0.z); a[3]=f2bf_rne(x0.w);
        a[4]=f2bf_rne(x1.x); a[5]=f2bf_rne(x1.y); a[6]=f2bf_rne(x1.z); a[7]=f2bf_rne(x1.w);
        b[0]=f2bf_rne(x2.x); b[1]=f2bf_rne(x2.y); b[2]=f2bf_rne(x2.z); b[3]=f2bf_rne(x2.w);
        b[4]=f2bf_rne(x3.x); b[5]=f2bf_rne(x3.y); b[6]=f2bf_rne(x3.z); b[7]=f2bf_rne(x3.w);
        *(u16x8*)&bb[key * 64 + (((c2    ) + key) & 7) * 8] = a;
        *(u16x8*)&bb[key * 64 + (((c2 + 1) + key) & 7) * 8] = b;
    }
    // V path: coalesced loads (thread owns d in [16dg,16dg+16) of one key),
    // 2-way LDS scatter (position spread by slot-chunk, d&7, and 2*dg)
    {
        int sl = (key & 51) | ((key & 4) << 1) | ((key & 8) >> 1);  // bits2<->3
        int sh = sl >> 3, sw = sl & 7;
        const float* vp = V + gbase + key * 64 + dg * 16;
        float4 y0 = *(const float4*)vp,       y1 = *(const float4*)(vp + 4);
        float4 y2 = *(const float4*)(vp + 8), y3 = *(const float4*)(vp + 12);
        float yy[16] = { y0.x,y0.y,y0.z,y0.w, y1.x,y1.y,y1.z,y1.w,
                         y2.x,y2.y,y2.z,y2.w, y3.x,y3.y,y3.z,y3.w };
        #pragma unroll
        for (int j = 0; j < 16; ++j) {
            int d = dg * 16 + j;
            int p = (sh + (j & 7) + 2 * dg) & 7;   // d&7==j&7, (d>>4)&3==dg
            lt[d * 64 + p * 8 + sw] = f2bf_rne(yy[j]);
        }
    }
    __syncthreads();
    {
        int o = tid * 16;
        *(u16x8*)&bb[4096 + o]     = *(const u16x8*)&lt[o];
        *(u16x8*)&bb[4096 + o + 8] = *(const u16x8*)&lt[o + 8];
    }
}

// ---- main: one wave per WG, 32 q-rows, no barriers ----
__global__ __launch_bounds__(64)
void bsattn_main(const float* __restrict__ Q, const float* __restrict__ SC,
                 const int* __restrict__ RS, const int* __restrict__ RE,
                 const u16* __restrict__ blob, float* __restrict__ O)
{
    constexpr int N = 2048, D = 64;
    int wg = blockIdx.x;
    int bh = wg & 31;
    int qs = 63 - (wg >> 5);             // LPT: heaviest stripes first
    int q0w = qs << 5;
    int lane = threadIdx.x;
    int n5 = lane & 31, h5 = lane >> 5;

    __shared__ __align__(16) u16 lsm[16384];   // 2 x 8KB-u16 tile buffers

    int myrow = q0w + n5;
    int rs_l = RS[myrow], re_l = RE[myrow];
    int w_rs_min = rs_l, w_rs_max = rs_l, w_re_min = re_l, w_re_max = re_l;
    #pragma unroll
    for (int o = 1; o < 32; o <<= 1) {
        w_rs_min = min(w_rs_min, __shfl_xor(w_rs_min, o));
        w_rs_max = max(w_rs_max, __shfl_xor(w_rs_max, o));
        w_re_min = min(w_re_min, __shfl_xor(w_re_min, o));
        w_re_max = max(w_re_max, __shfl_xor(w_re_max, o));
    }

    float sscale = SC[0] * 1.44269504088896340736f;   // exp2 domain

    // Q fragments: qf[s][j] = Q[myrow][16s + 8h5 + j] * sscale
    bf16x8 qf[4];
    {
        const float* qp = Q + ((size_t)bh * N + myrow) * D + h5 * 8;
        #pragma unroll
        for (int s = 0; s < 4; ++s) {
            float4 x0 = *(const float4*)(qp + 16 * s);
            float4 x1 = *(const float4*)(qp + 16 * s + 4);
            qf[s][0] = f2bf_rne(x0.x * sscale); qf[s][1] = f2bf_rne(x0.y * sscale);
            qf[s][2] = f2bf_rne(x0.z * sscale); qf[s][3] = f2bf_rne(x0.w * sscale);
            qf[s][4] = f2bf_rne(x1.x * sscale); qf[s][5] = f2bf_rne(x1.y * sscale);
            qf[s][6] = f2bf_rne(x1.z * sscale); qf[s][7] = f2bf_rne(x1.w * sscale);
        }
    }

    int kst = w_rs_min & ~63;
    int w   = (w_re_max - kst + 63) >> 6;

    // loop-invariant LDS offsets (u16): K pos=(2s+h5+row&7)&7, V adds 2*((d>>4)&3)
    int rot = (h5 + (n5 & 7)) & 7;
    int offK[2][4], offV[2][4];
    #pragma unroll
    for (int s = 0; s < 4; ++s) {
        offK[0][s] = n5 * 64        + (((2*s + rot)) & 7) * 8;
        offK[1][s] = (32 + n5) * 64 + (((2*s + rot)) & 7) * 8;
        int v0t = 2 * ((n5 >> 4) & 3);
        int v1t = 2 * ((2 + (n5 >> 4)) & 3);
        offV[0][s] = 4096 + n5 * 64        + ((2*s + rot + v0t) & 7) * 8;
        offV[1][s] = 4096 + (32 + n5) * 64 + ((2*s + rot + v1t) & 7) * 8;
    }

    f32x16 acc0, acc1, accl;
    #pragma unroll
    for (int r = 0; r < 16; ++r) { acc0[r] = 0.f; acc1[r] = 0.f; accl[r] = 0.f; }
    bf16x8 ones;
    #pragma unroll
    for (int j = 0; j < 8; ++j) ones[j] = (short)0x3F80;

    auto stage = [&](int i) {
        if (i < w) {
            const u16* src = blob + ((size_t)(bh * 32) + (kst >> 6) + i) * 8192;
            u16* dst = &lsm[(i & 1) << 13];
            #pragma unroll
            for (int cc = 0; cc < 16; ++cc)
                gload_lds16(src + cc * 512 + lane * 8, dst + cc * 512);
        }
    };

    auto proc = [&](int kb, const u16* ls) {
        f32x16 c0, c1;
        #pragma unroll
        for (int r = 0; r < 16; ++r) { c0[r] = 0.f; c1[r] = 0.f; }
        #pragma unroll
        for (int s = 0; s < 4; ++s) {
            c0 = MFMA32(*(const bf16x8*)&ls[offK[0][s]], qf[s], c0);
            c1 = MFMA32(*(const bf16x8*)&ls[offK[1][s]], qf[s], c1);
        }
        if (kb < w_rs_max || kb + 64 > w_re_min) {       // boundary tiles only
            #pragma unroll
            for (int r = 0; r < 16; ++r) {
                int key = kb + (r & 3) + 8 * (r >> 2) + 4 * h5;
                if (key < rs_l || key >= re_l)      c0[r] = -1e30f;
                if (key + 32 < rs_l || key + 32 >= re_l) c1[r] = -1e30f;
            }
        }
        bf16x8 pf[4];
        #pragma unroll
        for (int j = 0; j < 8; ++j) {
            pf[0][j] = (short)f2bf_fast(__builtin_amdgcn_exp2f(c0[j]));
            pf[1][j] = (short)f2bf_fast(__builtin_amdgcn_exp2f(c0[8 + j]));
            pf[2][j] = (short)f2bf_fast(__builtin_amdgcn_exp2f(c1[j]));
            pf[3][j] = (short)f2bf_fast(__builtin_amdgcn_exp2f(c1[8 + j]));
        }
        #pragma unroll
        for (int s = 0; s < 4; ++s) {
            acc0 = MFMA32(pf[s], *(const bf16x8*)&ls[offV[0][s]], acc0);
            acc1 = MFMA32(pf[s], *(const bf16x8*)&ls[offV[1][s]], acc1);
            accl = MFMA32(pf[s], ones, accl);
        }
    };

    stage(0);
    stage(1);
    for (int i = 0; i < w; ++i) {
        if (i + 1 < w) __builtin_amdgcn_s_waitcnt(0x7FF0);   // vmcnt(16): tile i landed
        else           __builtin_amdgcn_s_waitcnt(0x3FF0);   // vmcnt(0)
        __builtin_amdgcn_sched_barrier(0);
        proc(kst + (i << 6), &lsm[(i & 1) << 13]);
        stage(i + 2);    // reuses buf (i&1); proc's MFMAs already consumed it
    }

    // epilogue: row = (r&3)+8*(r>>2)+4h5 (same layout for acc and accl)
    #pragma unroll
    for (int r = 0; r < 16; ++r) {
        int row = (r & 3) + 8 * (r >> 2) + 4 * h5;
        float li = 1.0f / accl[r];
        float* rp = O + ((size_t)bh * N + q0w + row) * D + n5;
        rp[0]  = acc0[r] * li;
        rp[32] = acc1[r] * li;
    }
}

extern "C" void kernel_launch(void* const* d_in, const int* in_sizes, int n_in,
                              void* d_out, int out_size, void* d_ws, size_t ws_size,
                              hipStream_t stream) {
    const float* q  = (const float*)d_in[0];
    const float* k  = (const float*)d_in[1];
    const float* v  = (const float*)d_in[2];
    const float* sc = (const float*)d_in[3];
    const int* rs   = (const int*)d_in[4];
    const int* re   = (const int*)d_in[5];
    float* out      = (float*)d_out;
    u16* blob       = (u16*)d_ws;   // 32 bh * 32 tiles * 16KB = 16.8 MB

    prep_kernel<<<dim3(1024), dim3(256), 0, stream>>>(k, v, blob);
    bsattn_main<<<dim3(2048), dim3(64), 0, stream>>>(q, sc, rs, re, blob, out);
}